// Round 2
// baseline (4419.381 us; speedup 1.0000x reference)
//
#include <hip/hip_runtime.h>
#include <hip/hip_bf16.h>

// MambaSSMBlock: HID=1024, STATE=16, K=4, EXPAND=2, INNER=2048, B=4, L=4096
#define HID   1024
#define STATE 16
#define KCONV 4
#define INNER 2048
#define BSZ   4
#define LSEQ  4096
#define BL    (BSZ * LSEQ)       // 16384 rows
#define NCAT  2176               // 2048 (dt) + 16 (B) + 16 (C) + 96 pad -> 17 tiles of 128

typedef unsigned short ushort_t;
typedef unsigned int   uint_t;
typedef __attribute__((ext_vector_type(8))) __bf16 bf16x8;
typedef __attribute__((ext_vector_type(4))) float  f32x4;

// ---------- helpers ----------
__device__ __forceinline__ ushort_t f2bf(float f) {
    uint_t u = __float_as_uint(f);
    u += 0x7fffu + ((u >> 16) & 1u);       // RNE (finite values only here)
    return (ushort_t)(u >> 16);
}
__device__ __forceinline__ float bf2f(ushort_t h) {
    return __uint_as_float(((uint_t)h) << 16);
}

#define AS1 __attribute__((address_space(1)))
#define AS3 __attribute__((address_space(3)))
__device__ __forceinline__ void async_copy16(const ushort_t* g, ushort_t* l) {
    // LDS dest is wave-uniform base; HW writes lane i at base + i*16B
    __builtin_amdgcn_global_load_lds((const AS1 void*)g, (AS3 void*)l, 16, 0, 0);
}

// ---------- elementwise cast ----------
__global__ void cast_bf16_kernel(const float* __restrict__ src, ushort_t* __restrict__ dst, int n) {
    int i = blockIdx.x * 256 + threadIdx.x;
    if (i < n) dst[i] = f2bf(src[i]);
}

// ---------- build concatenated [dt_w; B_w; C_w; 0-pad] bf16 weight (NCAT x 2048) ----------
__global__ void build_wcat_kernel(const float* __restrict__ dtw, const float* __restrict__ Bw,
                                  const float* __restrict__ Cw, ushort_t* __restrict__ out) {
    int i = blockIdx.x * 256 + threadIdx.x;
    if (i >= NCAT * INNER) return;
    int r = i >> 11;           // / 2048
    int k = i & (INNER - 1);
    float v = 0.f;
    if (r < INNER)            v = dtw[i];
    else if (r < INNER + 16)  v = Bw[(r - INNER) * INNER + k];
    else if (r < INNER + 32)  v = Cw[(r - INNER - 16) * INNER + k];
    out[i] = f2bf(v);
}

__global__ void build_biascat_kernel(const float* __restrict__ dtb, const float* __restrict__ Bb,
                                     const float* __restrict__ Cb, float* __restrict__ out) {
    int i = blockIdx.x * 256 + threadIdx.x;
    if (i >= NCAT) return;
    float v = 0.f;
    if (i < INNER)            v = dtb[i];
    else if (i < INNER + 16)  v = Bb[i - INNER];
    else if (i < INNER + 32)  v = Cb[i - INNER - 16];
    out[i] = v;
}

// ---------- bf16 MFMA GEMM: C = A(M,K) @ B(N,K)^T, 128x128x32 tiles ----------
// MODE 0: in_proj  -> col<2048: x_part bf16 (oU0); col>=2048: silu(z) bf16 (oU1)
// MODE 1: dt/Bm/Cm -> col<2048: softplus -> dt bf16 (oU0); [2048,2064): Bm fp32; [2064,2080): Cm fp32
// MODE 2: out_proj -> plain bias add, fp32 to oF
#define BM 128
#define BN 128
#define BK 32

template <int MODE>
__global__ __launch_bounds__(256) void gemm_bt_kernel(
    const ushort_t* __restrict__ A, const ushort_t* __restrict__ Bw,
    const float* __restrict__ bias,
    ushort_t* __restrict__ oU0, ushort_t* __restrict__ oU1,
    float* __restrict__ oF, float* __restrict__ oB, float* __restrict__ oC,
    int N, int K)
{
    __shared__ ushort_t As[BM * BK];
    __shared__ ushort_t Bs[BN * BK];

    const int tid  = threadIdx.x;
    const int w    = tid >> 6;
    const int lane = tid & 63;
    const int row0 = blockIdx.y * BM;
    const int col0 = blockIdx.x * BN;

    const int m16 = lane & 15;
    const int ko8 = lane >> 4;

    // staging: wave w fills rows [w*32, w*32+32); lane i -> row i/4, cols (i&3)*8..+8
    const int srow  = w * 32 + (lane >> 2);
    const int scol8 = (lane & 3) * 8;

    f32x4 acc[4][4] = {};

    const int wr = (w >> 1) * 64;
    const int wc = (w & 1) * 64;

    for (int k0 = 0; k0 < K; k0 += BK) {
        const ushort_t* ga = A  + (size_t)(row0 + srow) * K + k0 + scol8;
        const ushort_t* gb = Bw + (size_t)(col0 + srow) * K + k0 + scol8;
        async_copy16(ga,                  &As[(w * 32) * BK]);
        async_copy16(ga + (size_t)16 * K, &As[(w * 32 + 16) * BK]);
        async_copy16(gb,                  &Bs[(w * 32) * BK]);
        async_copy16(gb + (size_t)16 * K, &Bs[(w * 32 + 16) * BK]);
        __syncthreads();   // compiler drains vmcnt before s_barrier

        bf16x8 af[4], bfr[4];
#pragma unroll
        for (int i = 0; i < 4; i++)
            af[i] = *(const bf16x8*)&As[(wr + i * 16 + m16) * BK + ko8 * 8];
#pragma unroll
        for (int j = 0; j < 4; j++)
            bfr[j] = *(const bf16x8*)&Bs[(wc + j * 16 + m16) * BK + ko8 * 8];
#pragma unroll
        for (int i = 0; i < 4; i++)
#pragma unroll
            for (int j = 0; j < 4; j++)
                acc[i][j] = __builtin_amdgcn_mfma_f32_16x16x32_bf16(af[i], bfr[j], acc[i][j], 0, 0, 0);
        __syncthreads();
    }

    // epilogue: C/D layout col = lane&15, row = (lane>>4)*4 + reg
    const int rbase = (lane >> 4) * 4;
#pragma unroll
    for (int i = 0; i < 4; i++) {
#pragma unroll
        for (int j = 0; j < 4; j++) {
#pragma unroll
            for (int r = 0; r < 4; r++) {
                int row = row0 + wr + i * 16 + rbase + r;
                int col = col0 + wc + j * 16 + m16;
                float v = acc[i][j][r] + bias[col];
                if (MODE == 0) {
                    if (col < INNER) {
                        oU0[(size_t)row * INNER + col] = f2bf(v);                // x_part bf16
                    } else {
                        float s = v / (1.f + __expf(-v));                        // silu(z)
                        oU1[(size_t)row * INNER + (col - INNER)] = f2bf(s);
                    }
                } else if (MODE == 1) {
                    if (col < INNER) {
                        float sp = fmaxf(v, 0.f) + log1pf(__expf(-fabsf(v)));    // softplus
                        oU0[(size_t)row * INNER + col] = f2bf(sp);               // dt bf16
                    } else if (col < INNER + 16) {
                        oB[(size_t)row * STATE + (col - INNER)] = v;             // Bm fp32
                    } else if (col < INNER + 32) {
                        oC[(size_t)row * STATE + (col - INNER - 16)] = v;        // Cm fp32
                    } // pad cols dropped
                } else {
                    oF[(size_t)row * N + col] = v;                               // d_out fp32
                }
            }
        }
    }
}

// ---------- causal depthwise conv (K=4) + silu; bf16 in, bf16 out ----------
__global__ void conv_silu_kernel(const ushort_t* __restrict__ xp, const float* __restrict__ cw,
                                 const float* __restrict__ cb,
                                 ushort_t* __restrict__ xcbf) {
    int i = blockIdx.x * 256 + threadIdx.x;     // over BL*INNER
    int d  = i & (INNER - 1);
    int bl = i >> 11;
    int l  = bl & (LSEQ - 1);
    float acc = cb[d];
#pragma unroll
    for (int k = 0; k < KCONV; k++) {
        int ls = l - (KCONV - 1) + k;
        if (ls >= 0) acc = fmaf(cw[d * KCONV + k], bf2f(xp[i + (ls - l) * INNER]), acc);
    }
    float s = acc / (1.f + __expf(-acc));
    xcbf[i] = f2bf(s);
}

// ---------- selective scan: lane per (d,s); 16-lane shuffle reduce over states ----------
// sz_y is read (silu(z)) then overwritten (gated y) at the same index by the same thread.
__global__ __launch_bounds__(256) void scan_kernel(
    const ushort_t* __restrict__ dt, const ushort_t* __restrict__ xc,
    const float* __restrict__ Bm, const float* __restrict__ Cm,
    const float* __restrict__ A_log, const float* __restrict__ Dv,
    ushort_t* sz_y)
{
    const int b   = blockIdx.y;                  // 4
    const int d0  = blockIdx.x * 16;             // 128 blocks of 16 channels
    const int tid = threadIdx.x;
    const int s   = tid & 15;
    const int d   = d0 + (tid >> 4);

    const float A  = -__expf(A_log[d * STATE + s]);
    const float Dd = Dv[d];
    float h = 0.f;
    const size_t base = (size_t)b * LSEQ;

#pragma unroll 4
    for (int t = 0; t < LSEQ; t++) {
        const size_t r = base + t;
        const float dtv = bf2f(dt[r * INNER + d]);
        const float xv  = bf2f(xc[r * INNER + d]);
        const float Bv  = Bm[r * STATE + s];
        const float Cv  = Cm[r * STATE + s];
        const float dA  = __expf(dtv * A);
        h = fmaf(dA, h, dtv * Bv * xv);
        float c = h * Cv;
        c += __shfl_xor(c, 8, 16);
        c += __shfl_xor(c, 4, 16);
        c += __shfl_xor(c, 2, 16);
        c += __shfl_xor(c, 1, 16);
        if (s == 0) {
            float y = c + Dd * xv;
            float g = y * bf2f(sz_y[r * INNER + d]);
            sz_y[r * INNER + d] = f2bf(g);
        }
    }
}

// ---------- launch ----------
extern "C" void kernel_launch(void* const* d_in, const int* in_sizes, int n_in,
                              void* d_out, int out_size, void* d_ws, size_t ws_size,
                              hipStream_t stream) {
    const float* x       = (const float*)d_in[0];
    const float* in_w    = (const float*)d_in[1];
    const float* in_b    = (const float*)d_in[2];
    const float* conv_w  = (const float*)d_in[3];
    const float* conv_b  = (const float*)d_in[4];
    const float* dt_w    = (const float*)d_in[5];
    const float* dt_b    = (const float*)d_in[6];
    const float* A_log   = (const float*)d_in[7];
    const float* B_w     = (const float*)d_in[8];
    const float* B_b     = (const float*)d_in[9];
    const float* C_w     = (const float*)d_in[10];
    const float* C_b     = (const float*)d_in[11];
    const float* Dv      = (const float*)d_in[12];
    const float* out_w   = (const float*)d_in[13];
    const float* out_b   = (const float*)d_in[14];
    float* out = (float*)d_out;

    char* ws = (char*)d_ws;
    size_t off = 0;
    auto alloc = [&](size_t bytes) { size_t o = off; off += (bytes + 255) & ~(size_t)255; return o; };

    ushort_t* Xbf     = (ushort_t*)(ws + alloc((size_t)BL * HID * 2));       // 32 MB
    ushort_t* W1bf    = (ushort_t*)(ws + alloc((size_t)2 * INNER * HID * 2));// 8 MB
    ushort_t* Wcat    = (ushort_t*)(ws + alloc((size_t)NCAT * INNER * 2));   // 8.5 MB
    ushort_t* Woutbf  = (ushort_t*)(ws + alloc((size_t)HID * INNER * 2));    // 4 MB
    float*    biascat = (float*)   (ws + alloc((size_t)NCAT * 4));
    ushort_t* xpart   = (ushort_t*)(ws + alloc((size_t)BL * INNER * 2));     // 64 MB, reused as dt
    ushort_t* szbf    = (ushort_t*)(ws + alloc((size_t)BL * INNER * 2));     // 64 MB, y in-place
    ushort_t* xconvbf = (ushort_t*)(ws + alloc((size_t)BL * INNER * 2));     // 64 MB
    float*    Bmbuf   = (float*)   (ws + alloc((size_t)BL * STATE * 4));     // 1 MB
    float*    Cmbuf   = (float*)   (ws + alloc((size_t)BL * STATE * 4));     // 1 MB
    ushort_t* dtbuf   = xpart;   // x_part dead after conv
    (void)in_sizes; (void)n_in; (void)out_size;

    // If workspace is too small, skip launches: harness reports clean absmax
    // failure (== max|ref|) instead of a device page-fault core dump.
    if (ws_size < off) return;

    // casts / weight packing
    {
        int n = BL * HID;
        cast_bf16_kernel<<<(n + 255) / 256, 256, 0, stream>>>(x, Xbf, n);
        n = 2 * INNER * HID;
        cast_bf16_kernel<<<(n + 255) / 256, 256, 0, stream>>>(in_w, W1bf, n);
        n = HID * INNER;
        cast_bf16_kernel<<<(n + 255) / 256, 256, 0, stream>>>(out_w, Woutbf, n);
        n = NCAT * INNER;
        build_wcat_kernel<<<(n + 255) / 256, 256, 0, stream>>>(dt_w, B_w, C_w, Wcat);
        build_biascat_kernel<<<(NCAT + 255) / 256, 256, 0, stream>>>(dt_b, B_b, C_b, biascat);
    }

    // GEMM1: xz = x @ in_proj_w^T + b  -> x_part bf16, silu(z) bf16
    gemm_bt_kernel<0><<<dim3((2 * INNER) / BN, BL / BM), 256, 0, stream>>>(
        Xbf, W1bf, in_b, xpart, szbf, nullptr, nullptr, nullptr, 2 * INNER, HID);

    // causal depthwise conv + silu -> x_conv bf16
    conv_silu_kernel<<<(BL * INNER) / 256, 256, 0, stream>>>(xpart, conv_w, conv_b, xconvbf);

    // GEMM2: [dt_pre | Bm | Cm] = x_conv @ Wcat^T + biascat ; softplus fused for dt
    gemm_bt_kernel<1><<<dim3(NCAT / BN, BL / BM), 256, 0, stream>>>(
        xconvbf, Wcat, biascat, dtbuf, nullptr, nullptr, Bmbuf, Cmbuf, NCAT, INNER);

    // selective scan (+ D*x, * silu(z)) -> y_gated bf16 (in-place over silu(z))
    scan_kernel<<<dim3(INNER / 16, BSZ), 256, 0, stream>>>(
        dtbuf, xconvbf, Bmbuf, Cmbuf, A_log, Dv, szbf);

    // GEMM3: out = y_gated @ out_w^T + out_b
    gemm_bt_kernel<2><<<dim3(HID / BN, BL / BM), 256, 0, stream>>>(
        szbf, Woutbf, out_b, nullptr, nullptr, out, nullptr, nullptr, HID, INNER);
}

// Round 3
// 2219.402 us; speedup vs baseline: 1.9912x; 1.9912x over previous
//
#include <hip/hip_runtime.h>
#include <hip/hip_bf16.h>

// MambaSSMBlock: HID=1024, STATE=16, K=4, EXPAND=2, INNER=2048, B=4, L=4096
#define HID   1024
#define STATE 16
#define KCONV 4
#define INNER 2048
#define BSZ   4
#define LSEQ  4096
#define BL    (BSZ * LSEQ)       // 16384 rows
#define NCAT  2176               // 2048 (dt) + 16 (B) + 16 (C) + 96 pad -> 17 tiles of 128
#define NCH   64                 // scan chunks
#define TC    64                 // steps per chunk (NCH*TC == LSEQ)

typedef unsigned short ushort_t;
typedef unsigned int   uint_t;
typedef __attribute__((ext_vector_type(8))) __bf16 bf16x8;
typedef __attribute__((ext_vector_type(4))) float  f32x4;

// ---------- helpers ----------
__device__ __forceinline__ ushort_t f2bf(float f) {
    uint_t u = __float_as_uint(f);
    u += 0x7fffu + ((u >> 16) & 1u);       // RNE (finite values only here)
    return (ushort_t)(u >> 16);
}
__device__ __forceinline__ float bf2f(ushort_t h) {
    return __uint_as_float(((uint_t)h) << 16);
}

#define AS1 __attribute__((address_space(1)))
#define AS3 __attribute__((address_space(3)))
__device__ __forceinline__ void async_copy16(const ushort_t* g, ushort_t* l) {
    // LDS dest is wave-uniform base; HW writes lane i at base + i*16B
    __builtin_amdgcn_global_load_lds((const AS1 void*)g, (AS3 void*)l, 16, 0, 0);
}

// ---------- elementwise cast ----------
__global__ void cast_bf16_kernel(const float* __restrict__ src, ushort_t* __restrict__ dst, int n) {
    int i = blockIdx.x * 256 + threadIdx.x;
    if (i < n) dst[i] = f2bf(src[i]);
}

// ---------- build concatenated [dt_w; B_w; C_w; 0-pad] bf16 weight (NCAT x 2048) ----------
__global__ void build_wcat_kernel(const float* __restrict__ dtw, const float* __restrict__ Bw,
                                  const float* __restrict__ Cw, ushort_t* __restrict__ out) {
    int i = blockIdx.x * 256 + threadIdx.x;
    if (i >= NCAT * INNER) return;
    int r = i >> 11;           // / 2048
    int k = i & (INNER - 1);
    float v = 0.f;
    if (r < INNER)            v = dtw[i];
    else if (r < INNER + 16)  v = Bw[(r - INNER) * INNER + k];
    else if (r < INNER + 32)  v = Cw[(r - INNER - 16) * INNER + k];
    out[i] = f2bf(v);
}

__global__ void build_biascat_kernel(const float* __restrict__ dtb, const float* __restrict__ Bb,
                                     const float* __restrict__ Cb, float* __restrict__ out) {
    int i = blockIdx.x * 256 + threadIdx.x;
    if (i >= NCAT) return;
    float v = 0.f;
    if (i < INNER)            v = dtb[i];
    else if (i < INNER + 16)  v = Bb[i - INNER];
    else if (i < INNER + 32)  v = Cb[i - INNER - 16];
    out[i] = v;
}

// ---------- bf16 MFMA GEMM: C = A(M,K) @ B(N,K)^T, 128x128x32 tiles ----------
// MODE 0: in_proj  -> col<2048: x_part bf16 (oU0); col>=2048: silu(z) bf16 (oU1)
// MODE 1: dt/Bm/Cm -> col<2048: softplus -> dt bf16 (oU0); [2048,2064): Bm fp32; [2064,2080): Cm fp32
// MODE 2: out_proj -> plain bias add, fp32 to oF
#define BM 128
#define BN 128
#define BK 32

template <int MODE>
__global__ __launch_bounds__(256) void gemm_bt_kernel(
    const ushort_t* __restrict__ A, const ushort_t* __restrict__ Bw,
    const float* __restrict__ bias,
    ushort_t* __restrict__ oU0, ushort_t* __restrict__ oU1,
    float* __restrict__ oF, float* __restrict__ oB, float* __restrict__ oC,
    int N, int K)
{
    __shared__ ushort_t As[BM * BK];
    __shared__ ushort_t Bs[BN * BK];

    const int tid  = threadIdx.x;
    const int w    = tid >> 6;
    const int lane = tid & 63;
    const int row0 = blockIdx.y * BM;
    const int col0 = blockIdx.x * BN;

    const int m16 = lane & 15;
    const int ko8 = lane >> 4;

    // staging: wave w fills rows [w*32, w*32+32); lane i -> row i/4, cols (i&3)*8..+8
    const int srow  = w * 32 + (lane >> 2);
    const int scol8 = (lane & 3) * 8;

    f32x4 acc[4][4] = {};

    const int wr = (w >> 1) * 64;
    const int wc = (w & 1) * 64;

    for (int k0 = 0; k0 < K; k0 += BK) {
        const ushort_t* ga = A  + (size_t)(row0 + srow) * K + k0 + scol8;
        const ushort_t* gb = Bw + (size_t)(col0 + srow) * K + k0 + scol8;
        async_copy16(ga,                  &As[(w * 32) * BK]);
        async_copy16(ga + (size_t)16 * K, &As[(w * 32 + 16) * BK]);
        async_copy16(gb,                  &Bs[(w * 32) * BK]);
        async_copy16(gb + (size_t)16 * K, &Bs[(w * 32 + 16) * BK]);
        __syncthreads();   // compiler drains vmcnt before s_barrier

        bf16x8 af[4], bfr[4];
#pragma unroll
        for (int i = 0; i < 4; i++)
            af[i] = *(const bf16x8*)&As[(wr + i * 16 + m16) * BK + ko8 * 8];
#pragma unroll
        for (int j = 0; j < 4; j++)
            bfr[j] = *(const bf16x8*)&Bs[(wc + j * 16 + m16) * BK + ko8 * 8];
#pragma unroll
        for (int i = 0; i < 4; i++)
#pragma unroll
            for (int j = 0; j < 4; j++)
                acc[i][j] = __builtin_amdgcn_mfma_f32_16x16x32_bf16(af[i], bfr[j], acc[i][j], 0, 0, 0);
        __syncthreads();
    }

    // epilogue: C/D layout col = lane&15, row = (lane>>4)*4 + reg
    const int rbase = (lane >> 4) * 4;
#pragma unroll
    for (int i = 0; i < 4; i++) {
#pragma unroll
        for (int j = 0; j < 4; j++) {
#pragma unroll
            for (int r = 0; r < 4; r++) {
                int row = row0 + wr + i * 16 + rbase + r;
                int col = col0 + wc + j * 16 + m16;
                float v = acc[i][j][r] + bias[col];
                if (MODE == 0) {
                    if (col < INNER) {
                        oU0[(size_t)row * INNER + col] = f2bf(v);                // x_part bf16
                    } else {
                        float s = v / (1.f + __expf(-v));                        // silu(z)
                        oU1[(size_t)row * INNER + (col - INNER)] = f2bf(s);
                    }
                } else if (MODE == 1) {
                    if (col < INNER) {
                        float sp = fmaxf(v, 0.f) + log1pf(__expf(-fabsf(v)));    // softplus
                        oU0[(size_t)row * INNER + col] = f2bf(sp);               // dt bf16
                    } else if (col < INNER + 16) {
                        oB[(size_t)row * STATE + (col - INNER)] = v;             // Bm fp32
                    } else if (col < INNER + 32) {
                        oC[(size_t)row * STATE + (col - INNER - 16)] = v;        // Cm fp32
                    } // pad cols dropped
                } else {
                    oF[(size_t)row * N + col] = v;                               // d_out fp32
                }
            }
        }
    }
}

// ---------- causal depthwise conv (K=4) + silu; bf16 in, bf16 out ----------
__global__ void conv_silu_kernel(const ushort_t* __restrict__ xp, const float* __restrict__ cw,
                                 const float* __restrict__ cb,
                                 ushort_t* __restrict__ xcbf) {
    int i = blockIdx.x * 256 + threadIdx.x;     // over BL*INNER
    int d  = i & (INNER - 1);
    int bl = i >> 11;
    int l  = bl & (LSEQ - 1);
    float acc = cb[d];
#pragma unroll
    for (int k = 0; k < KCONV; k++) {
        int ls = l - (KCONV - 1) + k;
        if (ls >= 0) acc = fmaf(cw[d * KCONV + k], bf2f(xp[i + (ls - l) * INNER]), acc);
    }
    float s = acc / (1.f + __expf(-acc));
    xcbf[i] = f2bf(s);
}

// ---------- chunked parallel scan ----------
// Pass 1: per (b, chunk, d, s) local scan from h=0 over TC steps.
// Emits P = prod(dA) (bf16) and S = h_end (fp32).  Layout: [(b*NCH+c)*INNER+d]*STATE+s
__global__ __launch_bounds__(256) void scan_pass1(
    const ushort_t* __restrict__ dt, const ushort_t* __restrict__ xc,
    const float* __restrict__ Bm, const float* __restrict__ A_log,
    ushort_t* __restrict__ Pc, float* __restrict__ Sc)
{
    const int b  = blockIdx.z;
    const int c  = blockIdx.y;
    const int d0 = blockIdx.x * 16;
    const int tid = threadIdx.x;
    const int s   = tid & 15;
    const int d   = d0 + (tid >> 4);

    const float A = -__expf(A_log[d * STATE + s]);
    float h = 0.f, P = 1.f;
    const size_t base = (size_t)b * LSEQ + (size_t)c * TC;

#pragma unroll 8
    for (int t = 0; t < TC; t++) {
        const size_t r = base + t;
        const float dtv = bf2f(dt[r * INNER + d]);
        const float xv  = bf2f(xc[r * INNER + d]);
        const float Bv  = Bm[r * STATE + s];
        const float dA  = __expf(dtv * A);
        h = fmaf(dA, h, dtv * Bv * xv);
        P *= dA;
    }
    const size_t idx = ((size_t)(b * NCH + c) * INNER + d) * STATE + s;
    Pc[idx] = f2bf(P);
    Sc[idx] = h;
}

// Pass 2: exclusive scan over chunks (in-place: S becomes H = chunk-initial state).
__global__ __launch_bounds__(256) void scan_pass2(
    const ushort_t* __restrict__ Pc, float* Sc)
{
    const int i = blockIdx.x * 256 + threadIdx.x;      // over BSZ*INNER*STATE
    const int b   = i >> 15;                           // / (INNER*STATE)
    const int rem = i & (INNER * STATE - 1);
    float H = 0.f;
#pragma unroll 8
    for (int c = 0; c < NCH; c++) {
        const size_t idx = (size_t)(b * NCH + c) * (INNER * STATE) + rem;
        const float Pv = bf2f(Pc[idx]);
        const float Sv = Sc[idx];
        const float Hn = fmaf(Pv, H, Sv);
        Sc[idx] = H;                                   // exclusive: h at chunk start
        H = Hn;
    }
}

// Pass 3: re-run local scan seeded with H, produce gated y (in-place over silu(z)).
__global__ __launch_bounds__(256) void scan_pass3(
    const ushort_t* __restrict__ dt, const ushort_t* __restrict__ xc,
    const float* __restrict__ Bm, const float* __restrict__ Cm,
    const float* __restrict__ A_log, const float* __restrict__ Dv,
    const float* __restrict__ Hc, ushort_t* sz_y)
{
    const int b  = blockIdx.z;
    const int c  = blockIdx.y;
    const int d0 = blockIdx.x * 16;
    const int tid = threadIdx.x;
    const int s   = tid & 15;
    const int d   = d0 + (tid >> 4);

    const float A  = -__expf(A_log[d * STATE + s]);
    const float Dd = Dv[d];
    float h = Hc[((size_t)(b * NCH + c) * INNER + d) * STATE + s];
    const size_t base = (size_t)b * LSEQ + (size_t)c * TC;

#pragma unroll 4
    for (int t = 0; t < TC; t++) {
        const size_t r = base + t;
        const float dtv = bf2f(dt[r * INNER + d]);
        const float xv  = bf2f(xc[r * INNER + d]);
        const float Bv  = Bm[r * STATE + s];
        const float Cv  = Cm[r * STATE + s];
        const float dA  = __expf(dtv * A);
        h = fmaf(dA, h, dtv * Bv * xv);
        float cc = h * Cv;
        cc += __shfl_xor(cc, 8, 16);
        cc += __shfl_xor(cc, 4, 16);
        cc += __shfl_xor(cc, 2, 16);
        cc += __shfl_xor(cc, 1, 16);
        if (s == 0) {
            float y = cc + Dd * xv;
            float g = y * bf2f(sz_y[r * INNER + d]);
            sz_y[r * INNER + d] = f2bf(g);
        }
    }
}

// ---------- launch ----------
extern "C" void kernel_launch(void* const* d_in, const int* in_sizes, int n_in,
                              void* d_out, int out_size, void* d_ws, size_t ws_size,
                              hipStream_t stream) {
    const float* x       = (const float*)d_in[0];
    const float* in_w    = (const float*)d_in[1];
    const float* in_b    = (const float*)d_in[2];
    const float* conv_w  = (const float*)d_in[3];
    const float* conv_b  = (const float*)d_in[4];
    const float* dt_w    = (const float*)d_in[5];
    const float* dt_b    = (const float*)d_in[6];
    const float* A_log   = (const float*)d_in[7];
    const float* B_w     = (const float*)d_in[8];
    const float* B_b     = (const float*)d_in[9];
    const float* C_w     = (const float*)d_in[10];
    const float* C_b     = (const float*)d_in[11];
    const float* Dv      = (const float*)d_in[12];
    const float* out_w   = (const float*)d_in[13];
    const float* out_b   = (const float*)d_in[14];
    float* out = (float*)d_out;

    char* ws = (char*)d_ws;
    size_t off = 0;
    auto alloc = [&](size_t bytes) { size_t o = off; off += (bytes + 255) & ~(size_t)255; return o; };

    ushort_t* Xbf     = (ushort_t*)(ws + alloc((size_t)BL * HID * 2));       // 32 MB   [dead after GEMM1]
    ushort_t* W1bf    = (ushort_t*)(ws + alloc((size_t)2 * INNER * HID * 2));// 8 MB    [dead after GEMM1]
    ushort_t* Wcat    = (ushort_t*)(ws + alloc((size_t)NCAT * INNER * 2));   // 8.5 MB  [dead after GEMM2]
    ushort_t* Woutbf  = (ushort_t*)(ws + alloc((size_t)HID * INNER * 2));    // 4 MB
    float*    biascat = (float*)   (ws + alloc((size_t)NCAT * 4));
    ushort_t* xpart   = (ushort_t*)(ws + alloc((size_t)BL * INNER * 2));     // 64 MB, reused as dt
    ushort_t* szbf    = (ushort_t*)(ws + alloc((size_t)BL * INNER * 2));     // 64 MB, y in-place
    ushort_t* xconvbf = (ushort_t*)(ws + alloc((size_t)BL * INNER * 2));     // 64 MB
    float*    Bmbuf   = (float*)   (ws + alloc((size_t)BL * STATE * 4));     // 1 MB
    float*    Cmbuf   = (float*)   (ws + alloc((size_t)BL * STATE * 4));     // 1 MB
    ushort_t* dtbuf   = xpart;   // x_part dead after conv

    // Chunk-scan scratch overlays the dead Xbf/W1bf/Wcat region (48.5 MB):
    //   P bf16: 64*4*2048*16*2 = 16 MB at ws+0
    //   S fp32: 64*4*2048*16*4 = 32 MB right after  (16+32=48 MB <= 48.5 MB dead)
    ushort_t* Pbuf = (ushort_t*)ws;
    float*    Sbuf = (float*)(ws + (size_t)NCH * BSZ * INNER * STATE * 2);
    (void)in_sizes; (void)n_in; (void)out_size;

    // If workspace is too small, skip launches: harness reports clean absmax
    // failure (== max|ref|) instead of a device page-fault core dump.
    if (ws_size < off) return;

    // casts / weight packing
    {
        int n = BL * HID;
        cast_bf16_kernel<<<(n + 255) / 256, 256, 0, stream>>>(x, Xbf, n);
        n = 2 * INNER * HID;
        cast_bf16_kernel<<<(n + 255) / 256, 256, 0, stream>>>(in_w, W1bf, n);
        n = HID * INNER;
        cast_bf16_kernel<<<(n + 255) / 256, 256, 0, stream>>>(out_w, Woutbf, n);
        n = NCAT * INNER;
        build_wcat_kernel<<<(n + 255) / 256, 256, 0, stream>>>(dt_w, B_w, C_w, Wcat);
        build_biascat_kernel<<<(NCAT + 255) / 256, 256, 0, stream>>>(dt_b, B_b, C_b, biascat);
    }

    // GEMM1: xz = x @ in_proj_w^T + b  -> x_part bf16, silu(z) bf16
    gemm_bt_kernel<0><<<dim3((2 * INNER) / BN, BL / BM), 256, 0, stream>>>(
        Xbf, W1bf, in_b, xpart, szbf, nullptr, nullptr, nullptr, 2 * INNER, HID);

    // causal depthwise conv + silu -> x_conv bf16
    conv_silu_kernel<<<(BL * INNER) / 256, 256, 0, stream>>>(xpart, conv_w, conv_b, xconvbf);

    // GEMM2: [dt_pre | Bm | Cm] = x_conv @ Wcat^T + biascat ; softplus fused for dt
    gemm_bt_kernel<1><<<dim3(NCAT / BN, BL / BM), 256, 0, stream>>>(
        xconvbf, Wcat, biascat, dtbuf, nullptr, nullptr, Bmbuf, Cmbuf, NCAT, INNER);

    // chunked selective scan (+ D*x, * silu(z)) -> y_gated bf16 (in-place over silu(z))
    scan_pass1<<<dim3(INNER / 16, NCH, BSZ), 256, 0, stream>>>(
        dtbuf, xconvbf, Bmbuf, A_log, Pbuf, Sbuf);
    scan_pass2<<<(BSZ * INNER * STATE) / 256, 256, 0, stream>>>(Pbuf, Sbuf);
    scan_pass3<<<dim3(INNER / 16, NCH, BSZ), 256, 0, stream>>>(
        dtbuf, xconvbf, Bmbuf, Cmbuf, A_log, Dv, Sbuf, szbf);

    // GEMM3: out = y_gated @ out_w^T + out_b
    gemm_bt_kernel<2><<<dim3(HID / BN, BL / BM), 256, 0, stream>>>(
        szbf, Woutbf, out_b, nullptr, nullptr, out, nullptr, nullptr, HID, INNER);
}

// Round 4
// 1238.379 us; speedup vs baseline: 3.5687x; 1.7922x over previous
//
#include <hip/hip_runtime.h>
#include <hip/hip_bf16.h>

// MambaSSMBlock: HID=1024, STATE=16, K=4, EXPAND=2, INNER=2048, B=4, L=4096
#define HID   1024
#define STATE 16
#define KCONV 4
#define INNER 2048
#define BSZ   4
#define LSEQ  4096
#define BL    (BSZ * LSEQ)       // 16384 rows
#define NCAT  2176               // 2048 (dt) + 16 (B) + 16 (C) + 96 pad -> 17 tiles of 128
#define NCH   64                 // scan chunks
#define TC    64                 // steps per chunk (NCH*TC == LSEQ)

typedef unsigned short ushort_t;
typedef unsigned int   uint_t;
typedef __attribute__((ext_vector_type(8))) __bf16 bf16x8;
typedef __attribute__((ext_vector_type(4))) float  f32x4;
typedef __attribute__((ext_vector_type(8))) unsigned short u16x8;

// ---------- helpers ----------
__device__ __forceinline__ ushort_t f2bf(float f) {
    uint_t u = __float_as_uint(f);
    u += 0x7fffu + ((u >> 16) & 1u);       // RNE (finite values only here)
    return (ushort_t)(u >> 16);
}
__device__ __forceinline__ float bf2f(ushort_t h) {
    return __uint_as_float(((uint_t)h) << 16);
}

#define AS1 __attribute__((address_space(1)))
#define AS3 __attribute__((address_space(3)))
__device__ __forceinline__ void async_copy16(const ushort_t* g, ushort_t* l) {
    // LDS dest is wave-uniform base; HW writes lane i at base + i*16B
    __builtin_amdgcn_global_load_lds((const AS1 void*)g, (AS3 void*)l, 16, 0, 0);
}

// ---------- elementwise cast ----------
__global__ void cast_bf16_kernel(const float* __restrict__ src, ushort_t* __restrict__ dst, int n) {
    int i = blockIdx.x * 256 + threadIdx.x;
    if (i < n) dst[i] = f2bf(src[i]);
}

// ---------- build concatenated [dt_w; B_w; C_w; 0-pad] bf16 weight (NCAT x 2048) ----------
__global__ void build_wcat_kernel(const float* __restrict__ dtw, const float* __restrict__ Bw,
                                  const float* __restrict__ Cw, ushort_t* __restrict__ out) {
    int i = blockIdx.x * 256 + threadIdx.x;
    if (i >= NCAT * INNER) return;
    int r = i >> 11;           // / 2048
    int k = i & (INNER - 1);
    float v = 0.f;
    if (r < INNER)            v = dtw[i];
    else if (r < INNER + 16)  v = Bw[(r - INNER) * INNER + k];
    else if (r < INNER + 32)  v = Cw[(r - INNER - 16) * INNER + k];
    out[i] = f2bf(v);
}

__global__ void build_biascat_kernel(const float* __restrict__ dtb, const float* __restrict__ Bb,
                                     const float* __restrict__ Cb, float* __restrict__ out) {
    int i = blockIdx.x * 256 + threadIdx.x;
    if (i >= NCAT) return;
    float v = 0.f;
    if (i < INNER)            v = dtb[i];
    else if (i < INNER + 16)  v = Bb[i - INNER];
    else if (i < INNER + 32)  v = Cb[i - INNER - 16];
    out[i] = v;
}

// ---------- bf16 MFMA GEMM: C = A(M,K) @ B(N,K)^T, 128x128x32 tiles ----------
// MODE 0: in_proj  -> col<2048: x_part bf16 (oU0); col>=2048: silu(z) bf16 (oU1)
// MODE 1: dt/Bm/Cm -> col<2048: softplus -> dt bf16 (oU0); [2048,2064): Bm fp32; [2064,2080): Cm fp32
// MODE 2: out_proj -> plain bias add, fp32 to oF
#define BM 128
#define BN 128
#define BK 32

template <int MODE>
__global__ __launch_bounds__(256) void gemm_bt_kernel(
    const ushort_t* __restrict__ A, const ushort_t* __restrict__ Bw,
    const float* __restrict__ bias,
    ushort_t* __restrict__ oU0, ushort_t* __restrict__ oU1,
    float* __restrict__ oF, float* __restrict__ oB, float* __restrict__ oC,
    int N, int K)
{
    __shared__ ushort_t As[BM * BK];
    __shared__ ushort_t Bs[BN * BK];

    const int tid  = threadIdx.x;
    const int w    = tid >> 6;
    const int lane = tid & 63;
    const int row0 = blockIdx.y * BM;
    const int col0 = blockIdx.x * BN;

    const int m16 = lane & 15;
    const int ko8 = lane >> 4;

    // staging: wave w fills rows [w*32, w*32+32); lane i -> row i/4, cols (i&3)*8..+8
    const int srow  = w * 32 + (lane >> 2);
    const int scol8 = (lane & 3) * 8;

    f32x4 acc[4][4] = {};

    const int wr = (w >> 1) * 64;
    const int wc = (w & 1) * 64;

    for (int k0 = 0; k0 < K; k0 += BK) {
        const ushort_t* ga = A  + (size_t)(row0 + srow) * K + k0 + scol8;
        const ushort_t* gb = Bw + (size_t)(col0 + srow) * K + k0 + scol8;
        async_copy16(ga,                  &As[(w * 32) * BK]);
        async_copy16(ga + (size_t)16 * K, &As[(w * 32 + 16) * BK]);
        async_copy16(gb,                  &Bs[(w * 32) * BK]);
        async_copy16(gb + (size_t)16 * K, &Bs[(w * 32 + 16) * BK]);
        __syncthreads();   // compiler drains vmcnt before s_barrier

        bf16x8 af[4], bfr[4];
#pragma unroll
        for (int i = 0; i < 4; i++)
            af[i] = *(const bf16x8*)&As[(wr + i * 16 + m16) * BK + ko8 * 8];
#pragma unroll
        for (int j = 0; j < 4; j++)
            bfr[j] = *(const bf16x8*)&Bs[(wc + j * 16 + m16) * BK + ko8 * 8];
#pragma unroll
        for (int i = 0; i < 4; i++)
#pragma unroll
            for (int j = 0; j < 4; j++)
                acc[i][j] = __builtin_amdgcn_mfma_f32_16x16x32_bf16(af[i], bfr[j], acc[i][j], 0, 0, 0);
        __syncthreads();
    }

    // epilogue: C/D layout col = lane&15, row = (lane>>4)*4 + reg
    const int rbase = (lane >> 4) * 4;
#pragma unroll
    for (int i = 0; i < 4; i++) {
#pragma unroll
        for (int j = 0; j < 4; j++) {
#pragma unroll
            for (int r = 0; r < 4; r++) {
                int row = row0 + wr + i * 16 + rbase + r;
                int col = col0 + wc + j * 16 + m16;
                float v = acc[i][j][r] + bias[col];
                if (MODE == 0) {
                    if (col < INNER) {
                        oU0[(size_t)row * INNER + col] = f2bf(v);                // x_part bf16
                    } else {
                        float s = v / (1.f + __expf(-v));                        // silu(z)
                        oU1[(size_t)row * INNER + (col - INNER)] = f2bf(s);
                    }
                } else if (MODE == 1) {
                    if (col < INNER) {
                        float sp = fmaxf(v, 0.f) + log1pf(__expf(-fabsf(v)));    // softplus
                        oU0[(size_t)row * INNER + col] = f2bf(sp);               // dt bf16
                    } else if (col < INNER + 16) {
                        oB[(size_t)row * STATE + (col - INNER)] = v;             // Bm fp32
                    } else if (col < INNER + 32) {
                        oC[(size_t)row * STATE + (col - INNER - 16)] = v;        // Cm fp32
                    } // pad cols dropped
                } else {
                    oF[(size_t)row * N + col] = v;                               // d_out fp32
                }
            }
        }
    }
}

// ---------- causal depthwise conv (K=4) + silu; bf16 in, bf16 out ----------
__global__ void conv_silu_kernel(const ushort_t* __restrict__ xp, const float* __restrict__ cw,
                                 const float* __restrict__ cb,
                                 ushort_t* __restrict__ xcbf) {
    int i = blockIdx.x * 256 + threadIdx.x;     // over BL*INNER
    int d  = i & (INNER - 1);
    int bl = i >> 11;
    int l  = bl & (LSEQ - 1);
    float acc = cb[d];
#pragma unroll
    for (int k = 0; k < KCONV; k++) {
        int ls = l - (KCONV - 1) + k;
        if (ls >= 0) acc = fmaf(cw[d * KCONV + k], bf2f(xp[i + (ls - l) * INNER]), acc);
    }
    float s = acc / (1.f + __expf(-acc));
    xcbf[i] = f2bf(s);
}

// ---------- chunked parallel scan, thread-per-channel ----------
// lane = channel d (64 consecutive per wave) -> dt/xc/sz loads fully coalesced.
// All 16 states live in registers; Bm/Cm rows are wave-uniform broadcasts.
// Pass 1: local scan from h=0; emits P[s]=exp(A[s]*sum_dt) bf16, S[s]=h_end fp32,
//         both stored contiguously per (b,c,d) -> coalesced vector stores.
__global__ __launch_bounds__(256) void scan_pass1(
    const ushort_t* __restrict__ dt, const ushort_t* __restrict__ xc,
    const float* __restrict__ Bm, const float* __restrict__ A_log,
    ushort_t* __restrict__ Pc, float* __restrict__ Sc)
{
    const int b = blockIdx.z;
    const int c = blockIdx.y;
    const int d = blockIdx.x * 256 + threadIdx.x;

    float A[STATE], h[STATE];
    {
        float al[STATE];
#pragma unroll
        for (int q = 0; q < 4; q++)
            *(f32x4*)(al + q * 4) = *(const f32x4*)(A_log + (size_t)d * STATE + q * 4);
#pragma unroll
        for (int s = 0; s < STATE; s++) { A[s] = -__expf(al[s]); h[s] = 0.f; }
    }
    float sdt = 0.f;
    const size_t base = (size_t)b * LSEQ + (size_t)c * TC;

#pragma unroll 2
    for (int t = 0; t < TC; t++) {
        const size_t r = base + t;
        const float dtv = bf2f(dt[r * INNER + d]);
        const float xv  = bf2f(xc[r * INNER + d]);
        const float dtx = dtv * xv;
        float Bv[STATE];
#pragma unroll
        for (int q = 0; q < 4; q++)
            *(f32x4*)(Bv + q * 4) = *(const f32x4*)(Bm + r * STATE + q * 4);
        sdt += dtv;
#pragma unroll
        for (int s = 0; s < STATE; s++) {
            const float dA = __expf(dtv * A[s]);
            h[s] = fmaf(dA, h[s], dtx * Bv[s]);
        }
    }

    const size_t idx = ((size_t)(b * NCH + c) * INNER + d) * STATE;
#pragma unroll
    for (int q = 0; q < 4; q++)
        *(f32x4*)(Sc + idx + q * 4) = *(const f32x4*)(h + q * 4);
    u16x8 p0, p1;
#pragma unroll
    for (int s = 0; s < 8; s++) { p0[s] = f2bf(__expf(A[s] * sdt)); }
#pragma unroll
    for (int s = 0; s < 8; s++) { p1[s] = f2bf(__expf(A[s + 8] * sdt)); }
    *(u16x8*)(Pc + idx)     = p0;
    *(u16x8*)(Pc + idx + 8) = p1;
}

// Pass 2: exclusive scan over chunks (in-place: S becomes H = chunk-initial state).
__global__ __launch_bounds__(256) void scan_pass2(
    const ushort_t* __restrict__ Pc, float* Sc)
{
    const int i = blockIdx.x * 256 + threadIdx.x;      // over BSZ*INNER*STATE
    const int b   = i >> 15;                           // / (INNER*STATE)
    const int rem = i & (INNER * STATE - 1);
    float H = 0.f;
#pragma unroll 8
    for (int c = 0; c < NCH; c++) {
        const size_t idx = (size_t)(b * NCH + c) * (INNER * STATE) + rem;
        const float Pv = bf2f(Pc[idx]);
        const float Sv = Sc[idx];
        const float Hn = fmaf(Pv, H, Sv);
        Sc[idx] = H;                                   // exclusive: h at chunk start
        H = Hn;
    }
}

// Pass 3: re-run local scan seeded with H; y = sum_s h[s]*C[s] + D*x; gate with
// silu(z) in-place. No shuffles: states are registers.
__global__ __launch_bounds__(256) void scan_pass3(
    const ushort_t* __restrict__ dt, const ushort_t* __restrict__ xc,
    const float* __restrict__ Bm, const float* __restrict__ Cm,
    const float* __restrict__ A_log, const float* __restrict__ Dv,
    const float* __restrict__ Hc, ushort_t* sz_y)
{
    const int b = blockIdx.z;
    const int c = blockIdx.y;
    const int d = blockIdx.x * 256 + threadIdx.x;

    float A[STATE], h[STATE];
    {
        float al[STATE];
#pragma unroll
        for (int q = 0; q < 4; q++)
            *(f32x4*)(al + q * 4) = *(const f32x4*)(A_log + (size_t)d * STATE + q * 4);
#pragma unroll
        for (int s = 0; s < STATE; s++) A[s] = -__expf(al[s]);
    }
    const size_t hidx = ((size_t)(b * NCH + c) * INNER + d) * STATE;
#pragma unroll
    for (int q = 0; q < 4; q++)
        *(f32x4*)(h + q * 4) = *(const f32x4*)(Hc + hidx + q * 4);

    const float Dd = Dv[d];
    const size_t base = (size_t)b * LSEQ + (size_t)c * TC;

#pragma unroll 2
    for (int t = 0; t < TC; t++) {
        const size_t r = base + t;
        const float dtv = bf2f(dt[r * INNER + d]);
        const float xv  = bf2f(xc[r * INNER + d]);
        const float dtx = dtv * xv;
        float Bv[STATE], Cv[STATE];
#pragma unroll
        for (int q = 0; q < 4; q++) {
            *(f32x4*)(Bv + q * 4) = *(const f32x4*)(Bm + r * STATE + q * 4);
            *(f32x4*)(Cv + q * 4) = *(const f32x4*)(Cm + r * STATE + q * 4);
        }
        float y = Dd * xv;
#pragma unroll
        for (int s = 0; s < STATE; s++) {
            const float dA = __expf(dtv * A[s]);
            h[s] = fmaf(dA, h[s], dtx * Bv[s]);
            y = fmaf(h[s], Cv[s], y);
        }
        const float zv = bf2f(sz_y[r * INNER + d]);
        sz_y[r * INNER + d] = f2bf(y * zv);
    }
}

// ---------- launch ----------
extern "C" void kernel_launch(void* const* d_in, const int* in_sizes, int n_in,
                              void* d_out, int out_size, void* d_ws, size_t ws_size,
                              hipStream_t stream) {
    const float* x       = (const float*)d_in[0];
    const float* in_w    = (const float*)d_in[1];
    const float* in_b    = (const float*)d_in[2];
    const float* conv_w  = (const float*)d_in[3];
    const float* conv_b  = (const float*)d_in[4];
    const float* dt_w    = (const float*)d_in[5];
    const float* dt_b    = (const float*)d_in[6];
    const float* A_log   = (const float*)d_in[7];
    const float* B_w     = (const float*)d_in[8];
    const float* B_b     = (const float*)d_in[9];
    const float* C_w     = (const float*)d_in[10];
    const float* C_b     = (const float*)d_in[11];
    const float* Dv      = (const float*)d_in[12];
    const float* out_w   = (const float*)d_in[13];
    const float* out_b   = (const float*)d_in[14];
    float* out = (float*)d_out;

    char* ws = (char*)d_ws;
    size_t off = 0;
    auto alloc = [&](size_t bytes) { size_t o = off; off += (bytes + 255) & ~(size_t)255; return o; };

    ushort_t* Xbf     = (ushort_t*)(ws + alloc((size_t)BL * HID * 2));       // 32 MB   [dead after GEMM1]
    ushort_t* W1bf    = (ushort_t*)(ws + alloc((size_t)2 * INNER * HID * 2));// 8 MB    [dead after GEMM1]
    ushort_t* Wcat    = (ushort_t*)(ws + alloc((size_t)NCAT * INNER * 2));   // 8.5 MB  [dead after GEMM2]
    ushort_t* Woutbf  = (ushort_t*)(ws + alloc((size_t)HID * INNER * 2));    // 4 MB
    float*    biascat = (float*)   (ws + alloc((size_t)NCAT * 4));
    ushort_t* xpart   = (ushort_t*)(ws + alloc((size_t)BL * INNER * 2));     // 64 MB, reused as dt
    ushort_t* szbf    = (ushort_t*)(ws + alloc((size_t)BL * INNER * 2));     // 64 MB, y in-place
    ushort_t* xconvbf = (ushort_t*)(ws + alloc((size_t)BL * INNER * 2));     // 64 MB
    float*    Bmbuf   = (float*)   (ws + alloc((size_t)BL * STATE * 4));     // 1 MB
    float*    Cmbuf   = (float*)   (ws + alloc((size_t)BL * STATE * 4));     // 1 MB
    ushort_t* dtbuf   = xpart;   // x_part dead after conv

    // Chunk-scan scratch overlays the dead Xbf/W1bf/Wcat region (~48.5 MB):
    //   P bf16: 16 MB at ws+0; S fp32: 32 MB after (48 MB total, fits)
    ushort_t* Pbuf = (ushort_t*)ws;
    float*    Sbuf = (float*)(ws + (size_t)NCH * BSZ * INNER * STATE * 2);
    (void)in_sizes; (void)n_in; (void)out_size;

    // If workspace is too small, skip launches: harness reports clean absmax
    // failure (== max|ref|) instead of a device page-fault core dump.
    if (ws_size < off) return;

    // casts / weight packing
    {
        int n = BL * HID;
        cast_bf16_kernel<<<(n + 255) / 256, 256, 0, stream>>>(x, Xbf, n);
        n = 2 * INNER * HID;
        cast_bf16_kernel<<<(n + 255) / 256, 256, 0, stream>>>(in_w, W1bf, n);
        n = HID * INNER;
        cast_bf16_kernel<<<(n + 255) / 256, 256, 0, stream>>>(out_w, Woutbf, n);
        n = NCAT * INNER;
        build_wcat_kernel<<<(n + 255) / 256, 256, 0, stream>>>(dt_w, B_w, C_w, Wcat);
        build_biascat_kernel<<<(NCAT + 255) / 256, 256, 0, stream>>>(dt_b, B_b, C_b, biascat);
    }

    // GEMM1: xz = x @ in_proj_w^T + b  -> x_part bf16, silu(z) bf16
    gemm_bt_kernel<0><<<dim3((2 * INNER) / BN, BL / BM), 256, 0, stream>>>(
        Xbf, W1bf, in_b, xpart, szbf, nullptr, nullptr, nullptr, 2 * INNER, HID);

    // causal depthwise conv + silu -> x_conv bf16
    conv_silu_kernel<<<(BL * INNER) / 256, 256, 0, stream>>>(xpart, conv_w, conv_b, xconvbf);

    // GEMM2: [dt_pre | Bm | Cm] = x_conv @ Wcat^T + biascat ; softplus fused for dt
    gemm_bt_kernel<1><<<dim3(NCAT / BN, BL / BM), 256, 0, stream>>>(
        xconvbf, Wcat, biascat, dtbuf, nullptr, nullptr, Bmbuf, Cmbuf, NCAT, INNER);

    // chunked selective scan (+ D*x, * silu(z)) -> y_gated bf16 (in-place over silu(z))
    scan_pass1<<<dim3(INNER / 256, NCH, BSZ), 256, 0, stream>>>(
        dtbuf, xconvbf, Bmbuf, A_log, Pbuf, Sbuf);
    scan_pass2<<<(BSZ * INNER * STATE) / 256, 256, 0, stream>>>(Pbuf, Sbuf);
    scan_pass3<<<dim3(INNER / 256, NCH, BSZ), 256, 0, stream>>>(
        dtbuf, xconvbf, Bmbuf, Cmbuf, A_log, Dv, Sbuf, szbf);

    // GEMM3: out = y_gated @ out_w^T + out_b
    gemm_bt_kernel<2><<<dim3(HID / BN, BL / BM), 256, 0, stream>>>(
        szbf, Woutbf, out_b, nullptr, nullptr, out, nullptr, nullptr, HID, INNER);
}

// Round 5
// 1217.281 us; speedup vs baseline: 3.6305x; 1.0173x over previous
//
#include <hip/hip_runtime.h>
#include <hip/hip_bf16.h>

// MambaSSMBlock: HID=1024, STATE=16, K=4, EXPAND=2, INNER=2048, B=4, L=4096
#define HID   1024
#define STATE 16
#define KCONV 4
#define INNER 2048
#define BSZ   4
#define LSEQ  4096
#define BL    (BSZ * LSEQ)       // 16384 rows
#define NCAT  2176               // 2048 (dt) + 16 (B) + 16 (C) + 96 pad -> 17 tiles of 128
#define NCH   64                 // scan chunks
#define TC    64                 // steps per chunk (NCH*TC == LSEQ)

typedef unsigned short ushort_t;
typedef unsigned int   uint_t;
typedef __attribute__((ext_vector_type(8))) __bf16 bf16x8;
typedef __attribute__((ext_vector_type(4))) float  f32x4;
typedef __attribute__((ext_vector_type(8))) unsigned short u16x8;

// ---------- helpers ----------
__device__ __forceinline__ ushort_t f2bf(float f) {
    uint_t u = __float_as_uint(f);
    u += 0x7fffu + ((u >> 16) & 1u);       // RNE (finite values only here)
    return (ushort_t)(u >> 16);
}
__device__ __forceinline__ float bf2f(ushort_t h) {
    return __uint_as_float(((uint_t)h) << 16);
}

#define AS1 __attribute__((address_space(1)))
#define AS3 __attribute__((address_space(3)))
__device__ __forceinline__ void async_copy16(const ushort_t* g, ushort_t* l) {
    // LDS dest is wave-uniform base; HW writes lane i at base + i*16B
    __builtin_amdgcn_global_load_lds((const AS1 void*)g, (AS3 void*)l, 16, 0, 0);
}

// ---------- elementwise cast ----------
__global__ void cast_bf16_kernel(const float* __restrict__ src, ushort_t* __restrict__ dst, int n) {
    int i = blockIdx.x * 256 + threadIdx.x;
    if (i < n) dst[i] = f2bf(src[i]);
}

// ---------- build concatenated [dt_w; B_w; C_w; 0-pad] bf16 weight (NCAT x 2048) ----------
__global__ void build_wcat_kernel(const float* __restrict__ dtw, const float* __restrict__ Bw,
                                  const float* __restrict__ Cw, ushort_t* __restrict__ out) {
    int i = blockIdx.x * 256 + threadIdx.x;
    if (i >= NCAT * INNER) return;
    int r = i >> 11;           // / 2048
    int k = i & (INNER - 1);
    float v = 0.f;
    if (r < INNER)            v = dtw[i];
    else if (r < INNER + 16)  v = Bw[(r - INNER) * INNER + k];
    else if (r < INNER + 32)  v = Cw[(r - INNER - 16) * INNER + k];
    out[i] = f2bf(v);
}

__global__ void build_biascat_kernel(const float* __restrict__ dtb, const float* __restrict__ Bb,
                                     const float* __restrict__ Cb, float* __restrict__ out) {
    int i = blockIdx.x * 256 + threadIdx.x;
    if (i >= NCAT) return;
    float v = 0.f;
    if (i < INNER)            v = dtb[i];
    else if (i < INNER + 16)  v = Bb[i - INNER];
    else if (i < INNER + 32)  v = Cb[i - INNER - 16];
    out[i] = v;
}

// ---------- bf16 MFMA GEMM: C = A(M,K) @ B(N,K)^T, 128x128x32 tiles ----------
// MODE 0: in_proj  -> col<2048: x_part bf16 (oU0); col>=2048: silu(z) bf16 (oU1)
// MODE 1: dt/Bm/Cm -> col<2048: softplus -> dt bf16 (oU0); [2048,2064): Bm fp32; [2064,2080): Cm fp32
// MODE 2: out_proj -> plain bias add, fp32 to oF
//
// XCD-banded swizzle: dispatch id lb -> xcd = lb%8 (HW round-robin heuristic),
// slot = lb/8. Each XCD owns a contiguous band of gridY/8 = 16 row-tiles,
// x-fastest within the band: A row-tiles are consumed by exactly one XCD by
// dispatch-adjacent blocks -> A fetched ~once; B re-reads hit per-XCD L2.
// Pure perf heuristic; mapping is a bijection so correctness is unaffected.
#define BM 128
#define BN 128
#define BK 32

template <int MODE>
__global__ __launch_bounds__(256) void gemm_bt_kernel(
    const ushort_t* __restrict__ A, const ushort_t* __restrict__ Bw,
    const float* __restrict__ bias,
    ushort_t* __restrict__ oU0, ushort_t* __restrict__ oU1,
    float* __restrict__ oF, float* __restrict__ oB, float* __restrict__ oC,
    int N, int K)
{
    __shared__ ushort_t As[BM * BK];
    __shared__ ushort_t Bs[BN * BK];

    const int tid  = threadIdx.x;
    const int w    = tid >> 6;
    const int lane = tid & 63;

    // ----- XCD-banded swizzle (gridDim.y == 128 for all launches here) -----
    const int nx   = gridDim.x;
    const int lb   = blockIdx.y * nx + blockIdx.x;   // dispatch linear id (x-fastest)
    const int xcd  = lb & 7;
    const int slot = lb >> 3;
    const int tx   = slot % nx;
    const int ty   = xcd * 16 + slot / nx;           // 16 row-tiles per XCD band
    const int row0 = ty * BM;
    const int col0 = tx * BN;

    const int m16 = lane & 15;
    const int ko8 = lane >> 4;

    // staging: wave w fills rows [w*32, w*32+32); lane i -> row i/4, cols (i&3)*8..+8
    const int srow  = w * 32 + (lane >> 2);
    const int scol8 = (lane & 3) * 8;

    f32x4 acc[4][4] = {};

    const int wr = (w >> 1) * 64;
    const int wc = (w & 1) * 64;

    for (int k0 = 0; k0 < K; k0 += BK) {
        const ushort_t* ga = A  + (size_t)(row0 + srow) * K + k0 + scol8;
        const ushort_t* gb = Bw + (size_t)(col0 + srow) * K + k0 + scol8;
        async_copy16(ga,                  &As[(w * 32) * BK]);
        async_copy16(ga + (size_t)16 * K, &As[(w * 32 + 16) * BK]);
        async_copy16(gb,                  &Bs[(w * 32) * BK]);
        async_copy16(gb + (size_t)16 * K, &Bs[(w * 32 + 16) * BK]);
        __syncthreads();   // compiler drains vmcnt before s_barrier

        bf16x8 af[4], bfr[4];
#pragma unroll
        for (int i = 0; i < 4; i++)
            af[i] = *(const bf16x8*)&As[(wr + i * 16 + m16) * BK + ko8 * 8];
#pragma unroll
        for (int j = 0; j < 4; j++)
            bfr[j] = *(const bf16x8*)&Bs[(wc + j * 16 + m16) * BK + ko8 * 8];
#pragma unroll
        for (int i = 0; i < 4; i++)
#pragma unroll
            for (int j = 0; j < 4; j++)
                acc[i][j] = __builtin_amdgcn_mfma_f32_16x16x32_bf16(af[i], bfr[j], acc[i][j], 0, 0, 0);
        __syncthreads();
    }

    // epilogue: C/D layout col = lane&15, row = (lane>>4)*4 + reg
    const int rbase = (lane >> 4) * 4;
#pragma unroll
    for (int i = 0; i < 4; i++) {
#pragma unroll
        for (int j = 0; j < 4; j++) {
#pragma unroll
            for (int r = 0; r < 4; r++) {
                int row = row0 + wr + i * 16 + rbase + r;
                int col = col0 + wc + j * 16 + m16;
                float v = acc[i][j][r] + bias[col];
                if (MODE == 0) {
                    if (col < INNER) {
                        oU0[(size_t)row * INNER + col] = f2bf(v);                // x_part bf16
                    } else {
                        float s = v / (1.f + __expf(-v));                        // silu(z)
                        oU1[(size_t)row * INNER + (col - INNER)] = f2bf(s);
                    }
                } else if (MODE == 1) {
                    if (col < INNER) {
                        float sp = fmaxf(v, 0.f) + log1pf(__expf(-fabsf(v)));    // softplus
                        oU0[(size_t)row * INNER + col] = f2bf(sp);               // dt bf16
                    } else if (col < INNER + 16) {
                        oB[(size_t)row * STATE + (col - INNER)] = v;             // Bm fp32
                    } else if (col < INNER + 32) {
                        oC[(size_t)row * STATE + (col - INNER - 16)] = v;        // Cm fp32
                    } // pad cols dropped
                } else {
                    oF[(size_t)row * N + col] = v;                               // d_out fp32
                }
            }
        }
    }
}

// ---------- causal depthwise conv (K=4) + silu; bf16 in, bf16 out ----------
__global__ void conv_silu_kernel(const ushort_t* __restrict__ xp, const float* __restrict__ cw,
                                 const float* __restrict__ cb,
                                 ushort_t* __restrict__ xcbf) {
    int i = blockIdx.x * 256 + threadIdx.x;     // over BL*INNER
    int d  = i & (INNER - 1);
    int bl = i >> 11;
    int l  = bl & (LSEQ - 1);
    float acc = cb[d];
#pragma unroll
    for (int k = 0; k < KCONV; k++) {
        int ls = l - (KCONV - 1) + k;
        if (ls >= 0) acc = fmaf(cw[d * KCONV + k], bf2f(xp[i + (ls - l) * INNER]), acc);
    }
    float s = acc / (1.f + __expf(-acc));
    xcbf[i] = f2bf(s);
}

// ---------- chunked parallel scan, thread-per-channel ----------
__global__ __launch_bounds__(256) void scan_pass1(
    const ushort_t* __restrict__ dt, const ushort_t* __restrict__ xc,
    const float* __restrict__ Bm, const float* __restrict__ A_log,
    ushort_t* __restrict__ Pc, float* __restrict__ Sc)
{
    const int b = blockIdx.z;
    const int c = blockIdx.y;
    const int d = blockIdx.x * 256 + threadIdx.x;

    float A[STATE], h[STATE];
    {
        float al[STATE];
#pragma unroll
        for (int q = 0; q < 4; q++)
            *(f32x4*)(al + q * 4) = *(const f32x4*)(A_log + (size_t)d * STATE + q * 4);
#pragma unroll
        for (int s = 0; s < STATE; s++) { A[s] = -__expf(al[s]); h[s] = 0.f; }
    }
    float sdt = 0.f;
    const size_t base = (size_t)b * LSEQ + (size_t)c * TC;

#pragma unroll 2
    for (int t = 0; t < TC; t++) {
        const size_t r = base + t;
        const float dtv = bf2f(dt[r * INNER + d]);
        const float xv  = bf2f(xc[r * INNER + d]);
        const float dtx = dtv * xv;
        float Bv[STATE];
#pragma unroll
        for (int q = 0; q < 4; q++)
            *(f32x4*)(Bv + q * 4) = *(const f32x4*)(Bm + r * STATE + q * 4);
        sdt += dtv;
#pragma unroll
        for (int s = 0; s < STATE; s++) {
            const float dA = __expf(dtv * A[s]);
            h[s] = fmaf(dA, h[s], dtx * Bv[s]);
        }
    }

    const size_t idx = ((size_t)(b * NCH + c) * INNER + d) * STATE;
#pragma unroll
    for (int q = 0; q < 4; q++)
        *(f32x4*)(Sc + idx + q * 4) = *(const f32x4*)(h + q * 4);
    u16x8 p0, p1;
#pragma unroll
    for (int s = 0; s < 8; s++) { p0[s] = f2bf(__expf(A[s] * sdt)); }
#pragma unroll
    for (int s = 0; s < 8; s++) { p1[s] = f2bf(__expf(A[s + 8] * sdt)); }
    *(u16x8*)(Pc + idx)     = p0;
    *(u16x8*)(Pc + idx + 8) = p1;
}

// Pass 2: exclusive scan over chunks (in-place: S becomes H = chunk-initial state).
__global__ __launch_bounds__(256) void scan_pass2(
    const ushort_t* __restrict__ Pc, float* Sc)
{
    const int i = blockIdx.x * 256 + threadIdx.x;      // over BSZ*INNER*STATE
    const int b   = i >> 15;                           // / (INNER*STATE)
    const int rem = i & (INNER * STATE - 1);
    float H = 0.f;
#pragma unroll 8
    for (int c = 0; c < NCH; c++) {
        const size_t idx = (size_t)(b * NCH + c) * (INNER * STATE) + rem;
        const float Pv = bf2f(Pc[idx]);
        const float Sv = Sc[idx];
        const float Hn = fmaf(Pv, H, Sv);
        Sc[idx] = H;                                   // exclusive: h at chunk start
        H = Hn;
    }
}

// Pass 3: re-run local scan seeded with H; y = sum_s h[s]*C[s] + D*x; gate with
// silu(z) in-place. No shuffles: states are registers.
__global__ __launch_bounds__(256) void scan_pass3(
    const ushort_t* __restrict__ dt, const ushort_t* __restrict__ xc,
    const float* __restrict__ Bm, const float* __restrict__ Cm,
    const float* __restrict__ A_log, const float* __restrict__ Dv,
    const float* __restrict__ Hc, ushort_t* sz_y)
{
    const int b = blockIdx.z;
    const int c = blockIdx.y;
    const int d = blockIdx.x * 256 + threadIdx.x;

    float A[STATE], h[STATE];
    {
        float al[STATE];
#pragma unroll
        for (int q = 0; q < 4; q++)
            *(f32x4*)(al + q * 4) = *(const f32x4*)(A_log + (size_t)d * STATE + q * 4);
#pragma unroll
        for (int s = 0; s < STATE; s++) A[s] = -__expf(al[s]);
    }
    const size_t hidx = ((size_t)(b * NCH + c) * INNER + d) * STATE;
#pragma unroll
    for (int q = 0; q < 4; q++)
        *(f32x4*)(h + q * 4) = *(const f32x4*)(Hc + hidx + q * 4);

    const float Dd = Dv[d];
    const size_t base = (size_t)b * LSEQ + (size_t)c * TC;

#pragma unroll 2
    for (int t = 0; t < TC; t++) {
        const size_t r = base + t;
        const float dtv = bf2f(dt[r * INNER + d]);
        const float xv  = bf2f(xc[r * INNER + d]);
        const float dtx = dtv * xv;
        float Bv[STATE], Cv[STATE];
#pragma unroll
        for (int q = 0; q < 4; q++) {
            *(f32x4*)(Bv + q * 4) = *(const f32x4*)(Bm + r * STATE + q * 4);
            *(f32x4*)(Cv + q * 4) = *(const f32x4*)(Cm + r * STATE + q * 4);
        }
        float y = Dd * xv;
#pragma unroll
        for (int s = 0; s < STATE; s++) {
            const float dA = __expf(dtv * A[s]);
            h[s] = fmaf(dA, h[s], dtx * Bv[s]);
            y = fmaf(h[s], Cv[s], y);
        }
        const float zv = bf2f(sz_y[r * INNER + d]);
        sz_y[r * INNER + d] = f2bf(y * zv);
    }
}

// ---------- launch ----------
extern "C" void kernel_launch(void* const* d_in, const int* in_sizes, int n_in,
                              void* d_out, int out_size, void* d_ws, size_t ws_size,
                              hipStream_t stream) {
    const float* x       = (const float*)d_in[0];
    const float* in_w    = (const float*)d_in[1];
    const float* in_b    = (const float*)d_in[2];
    const float* conv_w  = (const float*)d_in[3];
    const float* conv_b  = (const float*)d_in[4];
    const float* dt_w    = (const float*)d_in[5];
    const float* dt_b    = (const float*)d_in[6];
    const float* A_log   = (const float*)d_in[7];
    const float* B_w     = (const float*)d_in[8];
    const float* B_b     = (const float*)d_in[9];
    const float* C_w     = (const float*)d_in[10];
    const float* C_b     = (const float*)d_in[11];
    const float* Dv      = (const float*)d_in[12];
    const float* out_w   = (const float*)d_in[13];
    const float* out_b   = (const float*)d_in[14];
    float* out = (float*)d_out;

    char* ws = (char*)d_ws;
    size_t off = 0;
    auto alloc = [&](size_t bytes) { size_t o = off; off += (bytes + 255) & ~(size_t)255; return o; };

    ushort_t* Xbf     = (ushort_t*)(ws + alloc((size_t)BL * HID * 2));       // 32 MB   [dead after GEMM1]
    ushort_t* W1bf    = (ushort_t*)(ws + alloc((size_t)2 * INNER * HID * 2));// 8 MB    [dead after GEMM1]
    ushort_t* Wcat    = (ushort_t*)(ws + alloc((size_t)NCAT * INNER * 2));   // 8.5 MB  [dead after GEMM2]
    ushort_t* Woutbf  = (ushort_t*)(ws + alloc((size_t)HID * INNER * 2));    // 4 MB
    float*    biascat = (float*)   (ws + alloc((size_t)NCAT * 4));
    ushort_t* xpart   = (ushort_t*)(ws + alloc((size_t)BL * INNER * 2));     // 64 MB, reused as dt
    ushort_t* szbf    = (ushort_t*)(ws + alloc((size_t)BL * INNER * 2));     // 64 MB, y in-place
    ushort_t* xconvbf = (ushort_t*)(ws + alloc((size_t)BL * INNER * 2));     // 64 MB
    float*    Bmbuf   = (float*)   (ws + alloc((size_t)BL * STATE * 4));     // 1 MB
    float*    Cmbuf   = (float*)   (ws + alloc((size_t)BL * STATE * 4));     // 1 MB
    ushort_t* dtbuf   = xpart;   // x_part dead after conv

    // Chunk-scan scratch overlays the dead Xbf/W1bf/Wcat region (~48.5 MB):
    //   P bf16: 16 MB at ws+0; S fp32: 32 MB after (48 MB total, fits)
    ushort_t* Pbuf = (ushort_t*)ws;
    float*    Sbuf = (float*)(ws + (size_t)NCH * BSZ * INNER * STATE * 2);
    (void)in_sizes; (void)n_in; (void)out_size;

    // If workspace is too small, skip launches: harness reports clean absmax
    // failure (== max|ref|) instead of a device page-fault core dump.
    if (ws_size < off) return;

    // casts / weight packing
    {
        int n = BL * HID;
        cast_bf16_kernel<<<(n + 255) / 256, 256, 0, stream>>>(x, Xbf, n);
        n = 2 * INNER * HID;
        cast_bf16_kernel<<<(n + 255) / 256, 256, 0, stream>>>(in_w, W1bf, n);
        n = HID * INNER;
        cast_bf16_kernel<<<(n + 255) / 256, 256, 0, stream>>>(out_w, Woutbf, n);
        n = NCAT * INNER;
        build_wcat_kernel<<<(n + 255) / 256, 256, 0, stream>>>(dt_w, B_w, C_w, Wcat);
        build_biascat_kernel<<<(NCAT + 255) / 256, 256, 0, stream>>>(dt_b, B_b, C_b, biascat);
    }

    // GEMM1: xz = x @ in_proj_w^T + b  -> x_part bf16, silu(z) bf16
    gemm_bt_kernel<0><<<dim3((2 * INNER) / BN, BL / BM), 256, 0, stream>>>(
        Xbf, W1bf, in_b, xpart, szbf, nullptr, nullptr, nullptr, 2 * INNER, HID);

    // causal depthwise conv + silu -> x_conv bf16
    conv_silu_kernel<<<(BL * INNER) / 256, 256, 0, stream>>>(xpart, conv_w, conv_b, xconvbf);

    // GEMM2: [dt_pre | Bm | Cm] = x_conv @ Wcat^T + biascat ; softplus fused for dt
    gemm_bt_kernel<1><<<dim3(NCAT / BN, BL / BM), 256, 0, stream>>>(
        xconvbf, Wcat, biascat, dtbuf, nullptr, nullptr, Bmbuf, Cmbuf, NCAT, INNER);

    // chunked selective scan (+ D*x, * silu(z)) -> y_gated bf16 (in-place over silu(z))
    scan_pass1<<<dim3(INNER / 256, NCH, BSZ), 256, 0, stream>>>(
        dtbuf, xconvbf, Bmbuf, A_log, Pbuf, Sbuf);
    scan_pass2<<<(BSZ * INNER * STATE) / 256, 256, 0, stream>>>(Pbuf, Sbuf);
    scan_pass3<<<dim3(INNER / 256, NCH, BSZ), 256, 0, stream>>>(
        dtbuf, xconvbf, Bmbuf, Cmbuf, A_log, Dv, Sbuf, szbf);

    // GEMM3: out = y_gated @ out_w^T + out_b
    gemm_bt_kernel<2><<<dim3(HID / BN, BL / BM), 256, 0, stream>>>(
        szbf, Woutbf, out_b, nullptr, nullptr, out, nullptr, nullptr, HID, INNER);
}